// Round 9
// baseline (281.183 us; speedup 1.0000x reference)
//
#include <hip/hip_runtime.h>
#include <math.h>

#define BB 32
#define CC 128
#define HH 64
#define WW 64
#define KK 4
#define OO 256
#define RED 32
#define HWSZ (HH*WW)
#define XT_W 66            // 64 + 2 halo, both rows and cols
#define GPLANE (XT_W*XT_W) // 4356 pixels per (b,g) plane

typedef __attribute__((ext_vector_type(8))) short bf16x8;
typedef __attribute__((ext_vector_type(4))) float f32x4;
typedef __attribute__((ext_vector_type(16))) float f32x16;

static __device__ __forceinline__ unsigned short f2bf(float f) {
    unsigned int u = __float_as_uint(f);
    u += 0x7FFF + ((u >> 16) & 1);   // RNE
    return (unsigned short)(u >> 16);
}

// async 16B global -> LDS (DMA path, no VGPR round-trip). LDS dest is
// wave-uniform base + lane*16 (our i = k*256+tid indexing satisfies this).
static __device__ __forceinline__ void async16(unsigned short* lds, const unsigned short* g) {
    __builtin_amdgcn_global_load_lds(
        (const __attribute__((address_space(1))) unsigned int*)g,
        (__attribute__((address_space(3))) unsigned int*)lds, 16, 0, 0);
}

// ---------- Kernel 1: transpose x -> xt[b][g][row][col][c'=32] (bf16, zero halo, g = c/32 MAJOR)
// + per-(b,h) pool partials.  (~21us, near HBM roofline; unchanged.)
__global__ __launch_bounds__(256) void transpose_pool(const float* __restrict__ x,
        unsigned short* __restrict__ xt, float* __restrict__ partial) {
    __shared__ float lt[CC][65];
    int h = blockIdx.x & 63;
    int b = blockIdx.x >> 6;
    const float* xb = x + ((size_t)b * CC * HH + h) * WW;
    for (int i = threadIdx.x; i < CC * 16; i += 256) {
        int c = i >> 4, f4 = i & 15;
        float4 v = *(const float4*)(xb + (size_t)c * HWSZ + f4 * 4);
        lt[c][f4 * 4 + 0] = v.x;
        lt[c][f4 * 4 + 1] = v.y;
        lt[c][f4 * 4 + 2] = v.z;
        lt[c][f4 * 4 + 3] = v.w;
    }
    __syncthreads();
    size_t bg = (size_t)b * 4;
    for (int i = threadIdx.x; i < 64 * 16; i += 256) {
        int ww = i >> 4, cs = i & 15;          // cs: 8-channel group, g = cs>>2
        bf16x8 pk;
#pragma unroll
        for (int j = 0; j < 8; ++j) pk[j] = (short)f2bf(lt[cs * 8 + j][ww]);
        *(bf16x8*)&xt[(((bg + (cs >> 2)) * XT_W + (h + 1)) * XT_W + (ww + 1)) * 32 + (cs & 3) * 8] = pk;
    }
    if (threadIdx.x < 32) {
        int cs = threadIdx.x & 15;
        int col = (threadIdx.x < 16) ? 0 : 65;
        *(f32x4*)&xt[(((bg + (cs >> 2)) * XT_W + (h + 1)) * XT_W + col) * 32 + (cs & 3) * 8] =
            (f32x4){0.f, 0.f, 0.f, 0.f};
    }
    if (h == 0 || h == 63) {
        int hr = (h == 0) ? 0 : 65;
        for (int i = threadIdx.x; i < XT_W * 16; i += 256) {
            int px = i >> 4, cs = i & 15;
            *(f32x4*)&xt[(((bg + (cs >> 2)) * XT_W + hr) * XT_W + px) * 32 + (cs & 3) * 8] =
                (f32x4){0.f, 0.f, 0.f, 0.f};
        }
    }
    if (threadIdx.x < CC) {
        float s = 0.f;
#pragma unroll
        for (int j = 0; j < WW; ++j) s += lt[threadIdx.x][j];   // stride-65 rows: conflict-free
        partial[(size_t)blockIdx.x * CC + threadIdx.x] = s;
    }
}

// ---------- Kernel 2: h-reduce partials + MLP + softmax -> att[B][K] ----------
__global__ void att_kernel(const float* __restrict__ partial,
        const float* __restrict__ w1, const float* __restrict__ b1,
        const float* __restrict__ w2, const float* __restrict__ b2,
        float* __restrict__ att) {
    int b = blockIdx.x;
    int tid = threadIdx.x;
    __shared__ float ps[CC];
    __shared__ float hs[RED];
    __shared__ float ls[KK];
    if (tid < CC) {
        const float* pp = partial + (size_t)b * HH * CC + tid;
        float s = 0.f;
#pragma unroll
        for (int h = 0; h < HH; ++h) s += pp[(size_t)h * CC];
        ps[tid] = s * (1.0f / (float)HWSZ);
    }
    __syncthreads();
    int r = tid >> 3, j = tid & 7;
    const float* w1r = w1 + r * CC + j * 16;
    float p = 0.f;
#pragma unroll
    for (int c = 0; c < 16; ++c) p = fmaf(ps[j * 16 + c], w1r[c], p);
    p += __shfl_xor(p, 1, 64);
    p += __shfl_xor(p, 2, 64);
    p += __shfl_xor(p, 4, 64);
    if (j == 0) hs[r] = fmaxf(p + b1[r], 0.f);
    __syncthreads();
    if (tid < KK) {
        float acc = b2[tid];
        const float* w2k = w2 + tid * RED;
#pragma unroll
        for (int rr = 0; rr < RED; ++rr) acc = fmaf(hs[rr], w2k[rr], acc);
        ls[tid] = acc;
    }
    __syncthreads();
    if (tid == 0) {
        float m = fmaxf(fmaxf(ls[0], ls[1]), fmaxf(ls[2], ls[3]));
        float e0 = expf(ls[0] - m), e1 = expf(ls[1] - m);
        float e2 = expf(ls[2] - m), e3 = expf(ls[3] - m);
        float inv = 1.0f / (e0 + e1 + e2 + e3);
        att[b * KK + 0] = e0 * inv; att[b * KK + 1] = e1 * inv;
        att[b * KK + 2] = e2 * inv; att[b * KK + 3] = e3 * inv;
    }
}

// ---------- Kernel 3: mix weights -> bf16 wk[b][g][t][o][c'=32]  (g = c/32 MAJOR) ----------
__global__ __launch_bounds__(256) void mix_kernel(const float* __restrict__ w,
        const float* __restrict__ att, unsigned short* __restrict__ wk) {
    int gid = blockIdx.x * 256 + threadIdx.x;
    int c = gid & 127;
    int o = (gid >> 7) & 255;
    int b = gid >> 15;
    float a[KK];
#pragma unroll
    for (int k = 0; k < KK; ++k) a[k] = att[b * KK + k];
    float mixed[9];
#pragma unroll
    for (int t = 0; t < 9; ++t) mixed[t] = 0.f;
#pragma unroll
    for (int k = 0; k < KK; ++k) {
        const float* p = w + (((size_t)k * OO + o) * CC + c) * 9;
#pragma unroll
        for (int t = 0; t < 9; ++t) mixed[t] = fmaf(a[k], p[t], mixed[t]);
    }
    size_t base = ((size_t)b * 4 + (c >> 5)) * 9;
#pragma unroll
    for (int t = 0; t < 9; ++t)
        wk[((base + t) * OO + o) * 32 + (c & 31)] = f2bf(mixed[t]);
}

// ---------- Kernel 4: MFMA implicit-GEMM conv ----------
// Ledger: R1 84; R2 93.5; R3 394(spill); R4 123; R5 93.4; R6 93; R8 32x32 86.5
// (total best 266). PMC model: per-CU/tap LDS 1152 cyc vs MFMA 1033 — the kernel
// is LDS-read/MFMA BALANCED; every scheduling variant converged to ~85-93us.
// Only lever: LDS bytes per FLOP.
// This round: 256o x 4row block, 4 waves, wave = 128o x 64pix, acc[4][4] f32x16
// (256 AGPR, launch_bounds(256,1) -> 512-reg budget, 1 wave/SIMD).
// Reads/mfma: 0.75 -> 0.5 (16 reads / 32 mfma per wave-tap). Per-CU/tap:
// LDS 768 < MFMA 1033 -> MFMA-bound (~31us floor). Grid 1024->512 (xt fetch
// halves). Risk: 1 wave/SIMD latency exposure; dbuf+unrolled body must hide it.
#define XS_C 32
#define AL_C 32
__global__ __launch_bounds__(256, 1) void conv_mfma(const unsigned short* __restrict__ xt,
        const unsigned short* __restrict__ wk, float* __restrict__ out) {
    __shared__ unsigned short xs[6 * XT_W * XS_C];      // 25344 B
    __shared__ unsigned short als[2][OO * AL_C];        // 32768 B -> 58112 total

    // XCD-contiguous swizzle: XCD x gets logical blocks x*64 .. x*64+63 (= 4 samples)
    int bid = blockIdx.x;
    int blk = (bid & 7) * 64 + (bid >> 3);
    int b  = blk >> 4;
    int rg = blk & 15;
    int r0 = rg * 4;

    int tid = threadIdx.x;
    int lane = tid & 63;
    int wid = tid >> 6;
    int wm = wid & 1;           // o half: 128 o's
    int wn = wid >> 1;          // output row pair (2 rows each)
    int l31 = lane & 31;
    int lh = lane >> 5;         // k-half selector

    f32x16 acc[4][4];
#pragma unroll
    for (int i = 0; i < 4; ++i)
#pragma unroll
        for (int j = 0; j < 4; ++j)
#pragma unroll
            for (int r = 0; r < 16; ++r) acc[i][j][r] = 0.f;

    const unsigned short* xt_b = xt + (size_t)b * 4 * GPLANE * 32;
    const unsigned short* wk_b = wk + (size_t)b * 4 * 9 * OO * 32;

    for (int g = 0; g < 4; ++g) {        // c0 = g*32
        __syncthreads();                 // prior tap-8 reads done before xs overwrite
        // stage xs: 6 rows x 66 cols x 32c, one dense 25.3KB stream
        const unsigned short* xsrc = xt_b + ((size_t)g * GPLANE + r0 * XT_W) * 32;
        for (int i = tid; i < 1584; i += 256) {
            int pix = i >> 2, seg = i & 3;
            int segg = seg ^ ((pix >> 1) & 3);
            async16(xs + i * 8, xsrc + pix * 32 + segg * 8);
        }
        // stage als[0] (tap 0): 256 o x 32c, dense 16KB (4 chunks/thread)
        const unsigned short* wsrc = wk_b + (size_t)g * 9 * OO * 32;
        {
            int idx = tid;
#pragma unroll
            for (int rep = 0; rep < 4; ++rep, idx += 256) {
                int o = idx >> 2, seg = idx & 3;
                int segg = seg ^ ((o >> 1) & 3);
                async16(als[0] + idx * 8, wsrc + o * 32 + segg * 8);
            }
        }
        __syncthreads();   // full drain: xs + als[0] resident

        for (int t = 0; t < 9; ++t) {
            // issue next tap's als into the other buffer (4 loads/thread, uniform)
            if (t < 8) {
                int idx = tid;
#pragma unroll
                for (int rep = 0; rep < 4; ++rep, idx += 256) {
                    int o = idx >> 2, seg = idx & 3;
                    int segg = seg ^ ((o >> 1) & 3);
                    async16(als[(t + 1) & 1] + idx * 8,
                            wsrc + ((size_t)(t + 1) * OO + o) * 32 + segg * 8);
                }
            }
            int kh = t / 3, kw = t - kh * 3;
            // A fragments: [m][kk], o-row = wm*128 + m*32 + l31, k-seg = kk*2 + lh
            bf16x8 af[4][2], bfv[4][2];
#pragma unroll
            for (int m = 0; m < 4; ++m) {
                int orow = wm * 128 + m * 32 + l31;
#pragma unroll
                for (int kk = 0; kk < 2; ++kk) {
                    int s = kk * 2 + lh;
                    af[m][kk] = *(const bf16x8*)&als[t & 1][orow * AL_C +
                                                           (s ^ ((orow >> 1) & 3)) * 8];
                }
            }
            // B fragments: [nf][kk], pixel row (wn*2 + nf>>1 + kh), col ((nf&1)*32 + l31 + kw)
#pragma unroll
            for (int nf = 0; nf < 4; ++nf) {
                int prow = wn * 2 + (nf >> 1) + kh;
                int pcol = (nf & 1) * 32 + l31 + kw;
                int pix = prow * XT_W + pcol;
#pragma unroll
                for (int kk = 0; kk < 2; ++kk) {
                    int s = kk * 2 + lh;
                    bfv[nf][kk] = *(const bf16x8*)&xs[pix * XS_C +
                                                      (s ^ ((pix >> 1) & 3)) * 8];
                }
            }
#pragma unroll
            for (int kk = 0; kk < 2; ++kk)
#pragma unroll
                for (int m = 0; m < 4; ++m)
#pragma unroll
                    for (int nf = 0; nf < 4; ++nf)
                        acc[m][nf] = __builtin_amdgcn_mfma_f32_32x32x16_bf16(
                            af[m][kk], bfv[nf][kk], acc[m][nf], 0, 0, 0);
            if (t < 8) __syncthreads();   // tap-t reads done; t+1 DMAs drained by barrier
        }
    }

    float* outb = out + (size_t)b * OO * HWSZ;
#pragma unroll
    for (int m = 0; m < 4; ++m)
#pragma unroll
        for (int nf = 0; nf < 4; ++nf) {
            int row = r0 + wn * 2 + (nf >> 1);
            int col = (nf & 1) * 32 + l31;
#pragma unroll
            for (int r = 0; r < 16; ++r) {
                int o = wm * 128 + m * 32 + (r & 3) + 8 * (r >> 2) + 4 * lh;
                __builtin_nontemporal_store(acc[m][nf][r],
                    &outb[(size_t)o * HWSZ + row * WW + col]);
            }
        }
}

extern "C" void kernel_launch(void* const* d_in, const int* in_sizes, int n_in,
                              void* d_out, int out_size, void* d_ws, size_t ws_size,
                              hipStream_t stream) {
    const float* x       = (const float*)d_in[0];
    const float* weights = (const float*)d_in[1];
    const float* w1      = (const float*)d_in[2];
    const float* b1      = (const float*)d_in[3];
    const float* w2      = (const float*)d_in[4];
    const float* b2      = (const float*)d_in[5];
    float* out = (float*)d_out;

    char* ws = (char*)d_ws;
    float* partial      = (float*)ws;                               // 2048*128*4 = 1 MB
    float* att          = (float*)(ws + 1048576);                   // 512 B
    unsigned short* wk  = (unsigned short*)(ws + 1048576 + 4096);   // 18.87 MB
    unsigned short* xtp = (unsigned short*)(ws + 1048576 + 4096 + 18874368); // 35.68 MB

    transpose_pool<<<BB * HH, 256, 0, stream>>>(x, xtp, partial);
    att_kernel<<<BB, 256, 0, stream>>>(partial, w1, b1, w2, b2, att);
    mix_kernel<<<BB * OO * CC / 256, 256, 0, stream>>>(weights, att, wk);
    conv_mfma<<<BB * 16, 256, 0, stream>>>(xtp, wk, out);
}

// Round 10
// 263.703 us; speedup vs baseline: 1.0663x; 1.0663x over previous
//
#include <hip/hip_runtime.h>
#include <math.h>

#define BB 32
#define CC 128
#define HH 64
#define WW 64
#define KK 4
#define OO 256
#define RED 32
#define HWSZ (HH*WW)
#define XT_W 66            // 64 + 2 halo, both rows and cols
#define GPLANE (XT_W*XT_W) // 4356 pixels per (b,g) plane

typedef __attribute__((ext_vector_type(8))) short bf16x8;
typedef __attribute__((ext_vector_type(4))) float f32x4;
typedef __attribute__((ext_vector_type(16))) float f32x16;

static __device__ __forceinline__ unsigned short f2bf(float f) {
    unsigned int u = __float_as_uint(f);
    u += 0x7FFF + ((u >> 16) & 1);   // RNE
    return (unsigned short)(u >> 16);
}

// async 16B global -> LDS (DMA path, no VGPR round-trip). LDS dest is
// wave-uniform base + lane*16 (our i = k*256+tid indexing satisfies this).
static __device__ __forceinline__ void async16(unsigned short* lds, const unsigned short* g) {
    __builtin_amdgcn_global_load_lds(
        (const __attribute__((address_space(1))) unsigned int*)g,
        (__attribute__((address_space(3))) unsigned int*)lds, 16, 0, 0);
}

// ---------- Kernel 1: transpose x -> xt[b][g][row][col][c'=32] (bf16, zero halo, g = c/32 MAJOR)
// + per-(b,h) pool partials.  (~21us, near HBM roofline; unchanged.)
__global__ __launch_bounds__(256) void transpose_pool(const float* __restrict__ x,
        unsigned short* __restrict__ xt, float* __restrict__ partial) {
    __shared__ float lt[CC][65];
    int h = blockIdx.x & 63;
    int b = blockIdx.x >> 6;
    const float* xb = x + ((size_t)b * CC * HH + h) * WW;
    for (int i = threadIdx.x; i < CC * 16; i += 256) {
        int c = i >> 4, f4 = i & 15;
        float4 v = *(const float4*)(xb + (size_t)c * HWSZ + f4 * 4);
        lt[c][f4 * 4 + 0] = v.x;
        lt[c][f4 * 4 + 1] = v.y;
        lt[c][f4 * 4 + 2] = v.z;
        lt[c][f4 * 4 + 3] = v.w;
    }
    __syncthreads();
    size_t bg = (size_t)b * 4;
    for (int i = threadIdx.x; i < 64 * 16; i += 256) {
        int ww = i >> 4, cs = i & 15;          // cs: 8-channel group, g = cs>>2
        bf16x8 pk;
#pragma unroll
        for (int j = 0; j < 8; ++j) pk[j] = (short)f2bf(lt[cs * 8 + j][ww]);
        *(bf16x8*)&xt[(((bg + (cs >> 2)) * XT_W + (h + 1)) * XT_W + (ww + 1)) * 32 + (cs & 3) * 8] = pk;
    }
    if (threadIdx.x < 32) {
        int cs = threadIdx.x & 15;
        int col = (threadIdx.x < 16) ? 0 : 65;
        *(f32x4*)&xt[(((bg + (cs >> 2)) * XT_W + (h + 1)) * XT_W + col) * 32 + (cs & 3) * 8] =
            (f32x4){0.f, 0.f, 0.f, 0.f};
    }
    if (h == 0 || h == 63) {
        int hr = (h == 0) ? 0 : 65;
        for (int i = threadIdx.x; i < XT_W * 16; i += 256) {
            int px = i >> 4, cs = i & 15;
            *(f32x4*)&xt[(((bg + (cs >> 2)) * XT_W + hr) * XT_W + px) * 32 + (cs & 3) * 8] =
                (f32x4){0.f, 0.f, 0.f, 0.f};
        }
    }
    if (threadIdx.x < CC) {
        float s = 0.f;
#pragma unroll
        for (int j = 0; j < WW; ++j) s += lt[threadIdx.x][j];   // stride-65 rows: conflict-free
        partial[(size_t)blockIdx.x * CC + threadIdx.x] = s;
    }
}

// ---------- Kernel 2: h-reduce partials + MLP + softmax -> att[B][K] ----------
__global__ void att_kernel(const float* __restrict__ partial,
        const float* __restrict__ w1, const float* __restrict__ b1,
        const float* __restrict__ w2, const float* __restrict__ b2,
        float* __restrict__ att) {
    int b = blockIdx.x;
    int tid = threadIdx.x;
    __shared__ float ps[CC];
    __shared__ float hs[RED];
    __shared__ float ls[KK];
    if (tid < CC) {
        const float* pp = partial + (size_t)b * HH * CC + tid;
        float s = 0.f;
#pragma unroll
        for (int h = 0; h < HH; ++h) s += pp[(size_t)h * CC];
        ps[tid] = s * (1.0f / (float)HWSZ);
    }
    __syncthreads();
    int r = tid >> 3, j = tid & 7;
    const float* w1r = w1 + r * CC + j * 16;
    float p = 0.f;
#pragma unroll
    for (int c = 0; c < 16; ++c) p = fmaf(ps[j * 16 + c], w1r[c], p);
    p += __shfl_xor(p, 1, 64);
    p += __shfl_xor(p, 2, 64);
    p += __shfl_xor(p, 4, 64);
    if (j == 0) hs[r] = fmaxf(p + b1[r], 0.f);
    __syncthreads();
    if (tid < KK) {
        float acc = b2[tid];
        const float* w2k = w2 + tid * RED;
#pragma unroll
        for (int rr = 0; rr < RED; ++rr) acc = fmaf(hs[rr], w2k[rr], acc);
        ls[tid] = acc;
    }
    __syncthreads();
    if (tid == 0) {
        float m = fmaxf(fmaxf(ls[0], ls[1]), fmaxf(ls[2], ls[3]));
        float e0 = expf(ls[0] - m), e1 = expf(ls[1] - m);
        float e2 = expf(ls[2] - m), e3 = expf(ls[3] - m);
        float inv = 1.0f / (e0 + e1 + e2 + e3);
        att[b * KK + 0] = e0 * inv; att[b * KK + 1] = e1 * inv;
        att[b * KK + 2] = e2 * inv; att[b * KK + 3] = e3 * inv;
    }
}

// ---------- Kernel 3: mix weights -> bf16 wk[b][g][t][o][c'=32]  (g = c/32 MAJOR) ----------
__global__ __launch_bounds__(256) void mix_kernel(const float* __restrict__ w,
        const float* __restrict__ att, unsigned short* __restrict__ wk) {
    int gid = blockIdx.x * 256 + threadIdx.x;
    int c = gid & 127;
    int o = (gid >> 7) & 255;
    int b = gid >> 15;
    float a[KK];
#pragma unroll
    for (int k = 0; k < KK; ++k) a[k] = att[b * KK + k];
    float mixed[9];
#pragma unroll
    for (int t = 0; t < 9; ++t) mixed[t] = 0.f;
#pragma unroll
    for (int k = 0; k < KK; ++k) {
        const float* p = w + (((size_t)k * OO + o) * CC + c) * 9;
#pragma unroll
        for (int t = 0; t < 9; ++t) mixed[t] = fmaf(a[k], p[t], mixed[t]);
    }
    size_t base = ((size_t)b * 4 + (c >> 5)) * 9;
#pragma unroll
    for (int t = 0; t < 9; ++t)
        wk[((base + t) * OO + o) * 32 + (c & 31)] = f2bf(mixed[t]);
}

// ---------- Kernel 4: MFMA implicit-GEMM conv ----------
// Ledger (conv us): R1 84; R2 counted-vmcnt+2bar 93.5; R3 spill 394; R4 global-A 123;
// R5 small-tile 93.4; R6 3-tap grp 93; R8 32x32 86.5 (total BEST 266); R9 1-wave 132.
// R8 PMC: MfmaUtil 36.6% x 86.5us = 31.6us = exact MFMA floor (fully amortized);
// LDS floor ~35-46us; residual ~1300 cyc/tap = __syncthreads vmcnt(0) drain eating
// cold-L2/HBM latency of the als DMAs. R2's counted-vmcnt failed because dbuf
// required TWO barriers/tap. Fix: TRIPLE-buffer als[3] -> at DMA-issue of tap t+1
// (buf (t+1)%3) the laggard waves read buf (t-1)%3 — disjoint — so ONE raw
// s_barrier/tap suffices with s_waitcnt vmcnt(2) (t+1's 2 loads stay in flight
// across the barrier; m201-pattern). vmcnt(0) only at tap 8 / g-boundaries.
// LDS 25.3+3x8 = 49.9KB -> still 2 blocks/CU. Geometry/swizzles/epilogue = R8.
#define XS_C 32
#define AL_C 32
__global__ __launch_bounds__(256, 2) void conv_mfma(const unsigned short* __restrict__ xt,
        const unsigned short* __restrict__ wk, float* __restrict__ out) {
    __shared__ unsigned short xs[6 * XT_W * XS_C];      // 25344 B
    __shared__ unsigned short als[3][128 * AL_C];       // 24576 B -> 49920 total

    // XCD-contiguous swizzle: XCD x gets logical blocks x*128 .. x*128+127 (= 4 samples)
    int bid = blockIdx.x;
    int blk = (bid & 7) * 128 + (bid >> 3);
    int b  = blk >> 5;
    int rg = (blk >> 1) & 15;   // ot fastest: both o-halves of a row-group adjacent
    int ot = blk & 1;
    int r0 = rg * 4;
    int o0 = ot * 128;

    int tid = threadIdx.x;
    int lane = tid & 63;
    int wid = tid >> 6;
    int wm = wid & 1;           // o half within block's 128
    int wn = wid >> 1;          // output row pair (2 rows each)
    int l31 = lane & 31;
    int lh = lane >> 5;         // k-half selector

    f32x16 acc[2][4];
#pragma unroll
    for (int i = 0; i < 2; ++i)
#pragma unroll
        for (int j = 0; j < 4; ++j)
#pragma unroll
            for (int r = 0; r < 16; ++r) acc[i][j][r] = 0.f;

    const unsigned short* xt_b = xt + (size_t)b * 4 * GPLANE * 32;
    const unsigned short* wk_b = wk + ((size_t)b * 4 * 9 * OO + o0) * 32;

    for (int g = 0; g < 4; ++g) {        // c0 = g*32
        __syncthreads();                 // full drain: prior g's reads done before overwrite
        // stage xs: 6 rows x 66 cols x 32c, one dense 25.3KB stream
        const unsigned short* xsrc = xt_b + ((size_t)g * GPLANE + r0 * XT_W) * 32;
        for (int i = tid; i < 1584; i += 256) {
            int pix = i >> 2, seg = i & 3;
            int segg = seg ^ ((pix >> 1) & 3);
            async16(xs + i * 8, xsrc + pix * 32 + segg * 8);
        }
        // stage als[0] (tap 0): 128 o x 32c, dense 8KB
        const unsigned short* wsrc = wk_b + (size_t)g * 9 * OO * 32;
        {
            int ch = tid;
#pragma unroll
            for (int rep = 0; rep < 2; ++rep, ch += 256) {
                int o = ch >> 2, seg = ch & 3;
                int segg = seg ^ ((o >> 1) & 3);
                async16(als[0] + ch * 8, wsrc + o * 32 + segg * 8);
            }
        }
        __syncthreads();   // full drain: xs + als[0] resident

#pragma unroll
        for (int t = 0; t < 9; ++t) {
            // issue next tap's als into buf (t+1)%3 (2 loads/thread, uniform count).
            // Laggard waves are at most in tap t-1's read phase (buf (t-1)%3) — disjoint.
            if (t < 8) {
                int nb = (t + 1) % 3;
                int ch = tid;
#pragma unroll
                for (int rep = 0; rep < 2; ++rep, ch += 256) {
                    int o = ch >> 2, seg = ch & 3;
                    int segg = seg ^ ((o >> 1) & 3);
                    async16(als[nb] + ch * 8,
                            wsrc + ((size_t)(t + 1) * OO + o) * 32 + segg * 8);
                }
                // wait own tap-t DMAs (issued last tap) done; t+1's 2 stay in flight
                asm volatile("s_waitcnt vmcnt(2)" ::: "memory");
            } else {
                asm volatile("s_waitcnt vmcnt(0)" ::: "memory");
            }
            __builtin_amdgcn_s_barrier();      // all waves' tap-t data in LDS
            asm volatile("" ::: "memory");     // no LDS reads hoist above barrier

            int kh = t / 3, kw = t - kh * 3;
            const unsigned short* alsb = als[t % 3];
            // A fragments: [m][kk], o-row = wm*64 + m*32 + l31, k-seg = kk*2 + lh
            bf16x8 af[2][2], bfv[4][2];
#pragma unroll
            for (int m = 0; m < 2; ++m) {
                int orow = wm * 64 + m * 32 + l31;
#pragma unroll
                for (int kk = 0; kk < 2; ++kk) {
                    int s = kk * 2 + lh;
                    af[m][kk] = *(const bf16x8*)&alsb[orow * AL_C +
                                                     (s ^ ((orow >> 1) & 3)) * 8];
                }
            }
            // B fragments: [nf][kk], pixel = row (wn*2 + nf>>1 + kh), col ((nf&1)*32 + l31 + kw)
#pragma unroll
            for (int nf = 0; nf < 4; ++nf) {
                int prow = wn * 2 + (nf >> 1) + kh;
                int pcol = (nf & 1) * 32 + l31 + kw;
                int pix = prow * XT_W + pcol;
#pragma unroll
                for (int kk = 0; kk < 2; ++kk) {
                    int s = kk * 2 + lh;
                    bfv[nf][kk] = *(const bf16x8*)&xs[pix * XS_C +
                                                      (s ^ ((pix >> 1) & 3)) * 8];
                }
            }
#pragma unroll
            for (int kk = 0; kk < 2; ++kk)
#pragma unroll
                for (int m = 0; m < 2; ++m)
#pragma unroll
                    for (int nf = 0; nf < 4; ++nf)
                        acc[m][nf] = __builtin_amdgcn_mfma_f32_32x32x16_bf16(
                            af[m][kk], bfv[nf][kk], acc[m][nf], 0, 0, 0);
            // no trailing barrier: next tap's top barrier (after its DMA issue)
            // provides the rendezvous; triple-buffer makes the early issue safe.
        }
    }

    float* outb = out + ((size_t)b * OO + o0) * HWSZ;
#pragma unroll
    for (int m = 0; m < 2; ++m)
#pragma unroll
        for (int nf = 0; nf < 4; ++nf) {
            int row = r0 + wn * 2 + (nf >> 1);
            int col = (nf & 1) * 32 + l31;
#pragma unroll
            for (int r = 0; r < 16; ++r) {
                int o = wm * 64 + m * 32 + (r & 3) + 8 * (r >> 2) + 4 * lh;
                __builtin_nontemporal_store(acc[m][nf][r],
                    &outb[(size_t)o * HWSZ + row * WW + col]);
            }
        }
}

extern "C" void kernel_launch(void* const* d_in, const int* in_sizes, int n_in,
                              void* d_out, int out_size, void* d_ws, size_t ws_size,
                              hipStream_t stream) {
    const float* x       = (const float*)d_in[0];
    const float* weights = (const float*)d_in[1];
    const float* w1      = (const float*)d_in[2];
    const float* b1      = (const float*)d_in[3];
    const float* w2      = (const float*)d_in[4];
    const float* b2      = (const float*)d_in[5];
    float* out = (float*)d_out;

    char* ws = (char*)d_ws;
    float* partial      = (float*)ws;                               // 2048*128*4 = 1 MB
    float* att          = (float*)(ws + 1048576);                   // 512 B
    unsigned short* wk  = (unsigned short*)(ws + 1048576 + 4096);   // 18.87 MB
    unsigned short* xtp = (unsigned short*)(ws + 1048576 + 4096 + 18874368); // 35.68 MB

    transpose_pool<<<BB * HH, 256, 0, stream>>>(x, xtp, partial);
    att_kernel<<<BB, 256, 0, stream>>>(partial, w1, b1, w2, b2, att);
    mix_kernel<<<BB * OO * CC / 256, 256, 0, stream>>>(weights, att, wk);
    conv_mfma<<<BB * 2 * 16, 256, 0, stream>>>(xtp, wk, out);
}